// Round 1
// baseline (268.675 us; speedup 1.0000x reference)
//
#include <hip/hip_runtime.h>
#include <hip/hip_bf16.h>

#define NROWS 8192
#define KD    1024

typedef __attribute__((ext_vector_type(8))) short bf16x8;
typedef __attribute__((ext_vector_type(4))) float f32x4;

// Normalized bf16 copies of x1 and x2 (16 MB each). Recomputed every call.
__device__ unsigned short g_x1n[(size_t)NROWS * KD];
__device__ unsigned short g_x2n[(size_t)NROWS * KD];

__device__ __forceinline__ unsigned short f2bf(float f) {
    union { float f; unsigned u; } x; x.f = f;
    return (unsigned short)((x.u + 0x7fffu + ((x.u >> 16) & 1u)) >> 16);  // RNE
}

// One block per row (16384 blocks). 256 threads * float4 = 1024 cols exactly.
__global__ __launch_bounds__(256) void norm_cast_kernel(const float* __restrict__ x1,
                                                        const float* __restrict__ x2) {
    int row = blockIdx.x;
    const float* src;
    unsigned short* dst;
    if (row < NROWS) { src = x1 + (size_t)row * KD;           dst = g_x1n + (size_t)row * KD; }
    else             { src = x2 + (size_t)(row - NROWS) * KD; dst = g_x2n + (size_t)(row - NROWS) * KD; }

    int t = threadIdx.x;
    float4 v = ((const float4*)src)[t];
    float s = v.x * v.x + v.y * v.y + v.z * v.z + v.w * v.w;
    #pragma unroll
    for (int off = 32; off > 0; off >>= 1) s += __shfl_down(s, off);

    __shared__ float red[4];
    if ((t & 63) == 0) red[t >> 6] = s;
    __syncthreads();
    float tot = red[0] + red[1] + red[2] + red[3];
    float inv = 1.0f / fmaxf(sqrtf(tot), 1e-8f);

    ushort4 o;
    o.x = f2bf(v.x * inv); o.y = f2bf(v.y * inv);
    o.z = f2bf(v.z * inv); o.w = f2bf(v.w * inv);
    ((ushort4*)dst)[t] = o;
}

__device__ __forceinline__ void gload_lds16(const unsigned short* g, unsigned short* l) {
    __builtin_amdgcn_global_load_lds((const __attribute__((address_space(1))) void*)g,
                                     (__attribute__((address_space(3))) void*)l,
                                     16, 0, 0);
}

#define BM 128
#define BN 128
#define BK 64

// C[m][n] = 20 * dot(x1n[m], x2n[n])   (B^T GEMM, m97 structure)
__global__ __launch_bounds__(256, 3) void gemm_bt_kernel(float* __restrict__ C) {
    __shared__ unsigned short As[BM * BK];   // [128][64] bf16, linear (global_load_lds dest)
    __shared__ unsigned short Bs[BN * BK];

    // XCD-aware bijective swizzle (nwg = 4096, divisible by 8)
    int bid = blockIdx.x;
    int cpx = gridDim.x >> 3;
    int swz = (bid & 7) * cpx + (bid >> 3);
    int bm = swz >> 6;          // 64 N-tiles per M-row
    int bn = swz & 63;

    int t    = threadIdx.x;
    int lane = t & 63;
    int wid  = t >> 6;
    int wm   = (wid >> 1) << 6;   // wave 2x2 grid, each owns 64x64
    int wn   = (wid & 1) << 6;

    const unsigned short* Ab = g_x1n + (size_t)(bm * BM) * KD;
    const unsigned short* Bb = g_x2n + (size_t)(bn * BN) * KD;

    int row8 = t >> 3;            // 0..31 (staging row within 32-row slab)
    int kc   = (t & 7) * 8;       // staging k-col (elements)

    f32x4 acc[4][4] = {};

    for (int k0 = 0; k0 < KD; k0 += BK) {
        __syncthreads();   // all waves done reading LDS from previous step
        #pragma unroll
        for (int i = 0; i < 4; ++i) {
            gload_lds16(Ab + (size_t)(i * 32 + row8) * KD + k0 + kc, As + t * 8 + i * 2048);
            gload_lds16(Bb + (size_t)(i * 32 + row8) * KD + k0 + kc, Bs + t * 8 + i * 2048);
        }
        __syncthreads();   // compiler drains vmcnt(0) before s_barrier -> tiles ready

        int r  = lane & 15;
        int kq = (lane >> 4) * 8;
        #pragma unroll
        for (int kk = 0; kk < BK; kk += 32) {
            bf16x8 a[4], b[4];
            #pragma unroll
            for (int i = 0; i < 4; ++i) {
                a[i] = *(const bf16x8*)(As + (wm + i * 16 + r) * BK + kk + kq);
                b[i] = *(const bf16x8*)(Bs + (wn + i * 16 + r) * BK + kk + kq);
            }
            #pragma unroll
            for (int mi = 0; mi < 4; ++mi)
                #pragma unroll
                for (int ni = 0; ni < 4; ++ni)
                    acc[mi][ni] = __builtin_amdgcn_mfma_f32_16x16x32_bf16(
                        a[mi], b[ni], acc[mi][ni], 0, 0, 0);
        }
    }

    // Epilogue: C/D layout col = lane&15, row = (lane>>4)*4 + j  (measured m89/m91)
    int cn = lane & 15;
    int rq = (lane >> 4) * 4;
    #pragma unroll
    for (int mi = 0; mi < 4; ++mi) {
        #pragma unroll
        for (int ni = 0; ni < 4; ++ni) {
            #pragma unroll
            for (int j = 0; j < 4; ++j) {
                int rr = bm * BM + wm + mi * 16 + rq + j;
                int cc = bn * BN + wn + ni * 16 + cn;
                C[(size_t)rr * NROWS + cc] = acc[mi][ni][j] * 20.0f;
            }
        }
    }
}

extern "C" void kernel_launch(void* const* d_in, const int* in_sizes, int n_in,
                              void* d_out, int out_size, void* d_ws, size_t ws_size,
                              hipStream_t stream) {
    (void)in_sizes; (void)n_in; (void)d_ws; (void)ws_size; (void)out_size;
    const float* x1 = (const float*)d_in[0];
    const float* x2 = (const float*)d_in[1];
    float* out = (float*)d_out;

    norm_cast_kernel<<<2 * NROWS, 256, 0, stream>>>(x1, x2);
    gemm_bt_kernel<<<(NROWS / BM) * (NROWS / BN), 256, 0, stream>>>(out);
}

// Round 2
// 182.208 us; speedup vs baseline: 1.4746x; 1.4746x over previous
//
#include <hip/hip_runtime.h>
#include <hip/hip_bf16.h>

#define NROWS 8192
#define KD    1024
#define NT    16   // K tiles of 64

typedef __attribute__((ext_vector_type(8))) short bf16x8;
typedef __attribute__((ext_vector_type(4))) float f32x4;

__device__ unsigned short g_x1n[(size_t)NROWS * KD];
__device__ unsigned short g_x2n[(size_t)NROWS * KD];

__device__ __forceinline__ unsigned short f2bf(float f) {
    union { float f; unsigned u; } x; x.f = f;
    return (unsigned short)((x.u + 0x7fffu + ((x.u >> 16) & 1u)) >> 16);  // RNE
}

__global__ __launch_bounds__(256) void norm_cast_kernel(const float* __restrict__ x1,
                                                        const float* __restrict__ x2) {
    int row = blockIdx.x;
    const float* src;
    unsigned short* dst;
    if (row < NROWS) { src = x1 + (size_t)row * KD;           dst = g_x1n + (size_t)row * KD; }
    else             { src = x2 + (size_t)(row - NROWS) * KD; dst = g_x2n + (size_t)(row - NROWS) * KD; }

    int t = threadIdx.x;
    float4 v = ((const float4*)src)[t];
    float s = v.x * v.x + v.y * v.y + v.z * v.z + v.w * v.w;
    #pragma unroll
    for (int off = 32; off > 0; off >>= 1) s += __shfl_down(s, off);

    __shared__ float red[4];
    if ((t & 63) == 0) red[t >> 6] = s;
    __syncthreads();
    float tot = red[0] + red[1] + red[2] + red[3];
    float inv = 1.0f / fmaxf(sqrtf(tot), 1e-8f);

    ushort4 o;
    o.x = f2bf(v.x * inv); o.y = f2bf(v.y * inv);
    o.z = f2bf(v.z * inv); o.w = f2bf(v.w * inv);
    ((ushort4*)dst)[t] = o;
}

__device__ __forceinline__ void gload_lds16(const unsigned short* g, unsigned short* l) {
    __builtin_amdgcn_global_load_lds((const __attribute__((address_space(1))) void*)g,
                                     (__attribute__((address_space(3))) void*)l,
                                     16, 0, 0);
}

#define BARX() do { asm volatile("" ::: "memory"); __builtin_amdgcn_s_barrier(); \
                    asm volatile("" ::: "memory"); } while (0)

#define MFMA16(a, b, c) __builtin_amdgcn_mfma_f32_16x16x32_bf16((a), (b), (c), 0, 0, 0)

struct Ctx {
    const unsigned short* Ablk;   // A block panel base (bm*256 rows)
    const unsigned short* Bblk;   // B block panel base (bn*256 rows)
    unsigned short* ldsf;         // &lds[0][0][0]
    int t;                        // threadIdx.x
    int trow;                     // t>>3 (staging row 0..63)
    int scol;                     // pre-swizzled source col element offset
    int aoff0, aoff1;             // A ds_read element offsets (kk=0 / kk=1), swizzled
    int boff0, boff1;             // B ds_read element offsets
    int wr, wch;                  // wave row (0..1), wave B-half (wc>>1)
};

// Stage one half-tile (128 rows x 64 k) = 2 x global_load_lds(16B) per thread.
// LDS dest is LINEAR; global source carries the inverse swizzle (scol).
__device__ __forceinline__ void stage_half(const Ctx& c, const unsigned short* mat,
                                           int hbit, int region, int Tk) {
    const unsigned short* src = mat + (size_t)(hbit * 128 + c.trow) * KD + Tk * 64 + c.scol;
    unsigned short* dst = c.ldsf + region * 8192 + c.t * 8;
    gload_lds16(src, dst);
    gload_lds16(src + (size_t)64 * KD, dst + 4096);
}

// One K-tile (BK=64): 4 phases (C-quadrants), 16 MFMA each.
// Stage: q0 -> (T+1).A0, q1 -> (T+1).A1, q2 -> (T+2).B0, q3 -> (T+2).B1
// (A halves of tile T are last read at q2, B halves at q1 -> all writes safe.)
template<int BUF, bool SA, bool SB, int WAITN>
__device__ __forceinline__ void tile_body(const Ctx& c, f32x4 (&acc)[8][4], int T) {
    const unsigned short* ab = c.ldsf + (BUF * 4 + 0) * 8192 + c.wr * 8192;
    const unsigned short* bb = c.ldsf + (BUF * 4 + 2) * 8192 + c.wch * 8192;
    bf16x8 Af[8], Bf[8];

    // ---- q0: read A mi0-3, B ni0-1; MFMA mi0-3 x ni0-1 ----
    #pragma unroll
    for (int mi = 0; mi < 4; ++mi) {
        Af[mi * 2 + 0] = *(const bf16x8*)(ab + mi * 1024 + c.aoff0);
        Af[mi * 2 + 1] = *(const bf16x8*)(ab + mi * 1024 + c.aoff1);
    }
    #pragma unroll
    for (int ni = 0; ni < 2; ++ni) {
        Bf[ni * 2 + 0] = *(const bf16x8*)(bb + ni * 1024 + c.boff0);
        Bf[ni * 2 + 1] = *(const bf16x8*)(bb + ni * 1024 + c.boff1);
    }
    if (SA) stage_half(c, c.Ablk, 0, ((BUF ^ 1) * 4 + 0), T + 1);
    BARX();
    __builtin_amdgcn_s_setprio(1);
    #pragma unroll
    for (int mi = 0; mi < 4; ++mi)
        #pragma unroll
        for (int ni = 0; ni < 2; ++ni) {
            acc[mi][ni] = MFMA16(Af[mi * 2 + 0], Bf[ni * 2 + 0], acc[mi][ni]);
            acc[mi][ni] = MFMA16(Af[mi * 2 + 1], Bf[ni * 2 + 1], acc[mi][ni]);
        }
    __builtin_amdgcn_s_setprio(0);
    BARX();

    // ---- q1: read B ni2-3; MFMA mi0-3 x ni2-3 ----
    #pragma unroll
    for (int ni = 2; ni < 4; ++ni) {
        Bf[ni * 2 + 0] = *(const bf16x8*)(bb + ni * 1024 + c.boff0);
        Bf[ni * 2 + 1] = *(const bf16x8*)(bb + ni * 1024 + c.boff1);
    }
    if (SA) stage_half(c, c.Ablk, 1, ((BUF ^ 1) * 4 + 1), T + 1);
    BARX();
    __builtin_amdgcn_s_setprio(1);
    #pragma unroll
    for (int mi = 0; mi < 4; ++mi)
        #pragma unroll
        for (int ni = 2; ni < 4; ++ni) {
            acc[mi][ni] = MFMA16(Af[mi * 2 + 0], Bf[ni * 2 + 0], acc[mi][ni]);
            acc[mi][ni] = MFMA16(Af[mi * 2 + 1], Bf[ni * 2 + 1], acc[mi][ni]);
        }
    __builtin_amdgcn_s_setprio(0);
    BARX();

    // ---- q2: read A mi4-7 (overwrite Af); MFMA mi4-7 x ni2-3 ----
    #pragma unroll
    for (int mi = 0; mi < 4; ++mi) {
        Af[mi * 2 + 0] = *(const bf16x8*)(ab + (mi + 4) * 1024 + c.aoff0);
        Af[mi * 2 + 1] = *(const bf16x8*)(ab + (mi + 4) * 1024 + c.aoff1);
    }
    if (SB) stage_half(c, c.Bblk, 0, (BUF * 4 + 2), T + 2);
    BARX();
    __builtin_amdgcn_s_setprio(1);
    #pragma unroll
    for (int mi = 0; mi < 4; ++mi)
        #pragma unroll
        for (int ni = 2; ni < 4; ++ni) {
            acc[mi + 4][ni] = MFMA16(Af[mi * 2 + 0], Bf[ni * 2 + 0], acc[mi + 4][ni]);
            acc[mi + 4][ni] = MFMA16(Af[mi * 2 + 1], Bf[ni * 2 + 1], acc[mi + 4][ni]);
        }
    __builtin_amdgcn_s_setprio(0);
    BARX();

    // ---- q3: MFMA mi4-7 x ni0-1 (no reads) ----
    if (SB) stage_half(c, c.Bblk, 1, (BUF * 4 + 3), T + 2);
    BARX();
    __builtin_amdgcn_s_setprio(1);
    #pragma unroll
    for (int mi = 0; mi < 4; ++mi)
        #pragma unroll
        for (int ni = 0; ni < 2; ++ni) {
            acc[mi + 4][ni] = MFMA16(Af[mi * 2 + 0], Bf[ni * 2 + 0], acc[mi + 4][ni]);
            acc[mi + 4][ni] = MFMA16(Af[mi * 2 + 1], Bf[ni * 2 + 1], acc[mi + 4][ni]);
        }
    __builtin_amdgcn_s_setprio(0);
    if (WAITN == 4)      asm volatile("s_waitcnt vmcnt(4)" ::: "memory");
    else if (WAITN == 0) asm volatile("s_waitcnt vmcnt(0)" ::: "memory");
    BARX();
}

// 256x256 tile, BK=64, 8 waves (2M x 4N), 8-phase counted-vmcnt schedule.
__global__ __launch_bounds__(512, 2) void gemm8_kernel(float* __restrict__ C) {
    __shared__ unsigned short lds[2][4][8192];   // [buf][A0,A1,B0,B1][128*64] = 128 KiB

    int bid = blockIdx.x;                 // 1024 blocks (32x32), 1024 % 8 == 0
    int swz = (bid & 7) * 128 + (bid >> 3);
    int bm = swz >> 5, bn = swz & 31;

    int t = threadIdx.x;
    int lane = t & 63, wid = t >> 6;
    int wr = wid >> 2, wc = wid & 3;
    int r = lane & 15;
    int s0 = (lane >> 4) ^ (r & 7);       // swizzled 16B slot, kk=0
    int s1 = s0 ^ 4;                      // kk=1

    Ctx c;
    c.Ablk = g_x1n + (size_t)bm * 256 * KD;
    c.Bblk = g_x2n + (size_t)bn * 256 * KD;
    c.ldsf = &lds[0][0][0];
    c.t = t;
    c.trow = t >> 3;
    c.scol = (((t & 7) ^ ((t >> 3) & 7))) * 8;   // inverse swizzle on global source
    c.aoff0 = r * 64 + s0 * 8;
    c.aoff1 = r * 64 + s1 * 8;
    c.boff0 = ((wc & 1) * 64 + r) * 64 + s0 * 8;
    c.boff1 = ((wc & 1) * 64 + r) * 64 + s1 * 8;
    c.wr = wr;
    c.wch = wc >> 1;

    f32x4 acc[8][4] = {};

    // Prologue: tile0 {B0,B1,A0,A1}, tile1 {B0,B1}; wait tile0 complete (4 newer in flight)
    stage_half(c, c.Bblk, 0, 2, 0);
    stage_half(c, c.Bblk, 1, 3, 0);
    stage_half(c, c.Ablk, 0, 0, 0);
    stage_half(c, c.Ablk, 1, 1, 0);
    stage_half(c, c.Bblk, 0, 6, 1);
    stage_half(c, c.Bblk, 1, 7, 1);
    asm volatile("s_waitcnt vmcnt(4)" ::: "memory");
    BARX();

    for (int it = 0; it < 7; ++it) {      // tiles 0..13, full staging
        tile_body<0, true, true, 4>(c, acc, 2 * it);
        tile_body<1, true, true, 4>(c, acc, 2 * it + 1);
    }
    tile_body<0, true, false, 0>(c, acc, 14);   // stages (15).A0/A1, drain
    tile_body<1, false, false, -1>(c, acc, 15);

    // Epilogue: C/D layout col = lane&15, row = (lane>>4)*4 + j
    int cn = lane & 15, rq = (lane >> 4) * 4;
    int rbase = bm * 256 + wr * 128;
    int cbase = bn * 256 + wc * 64;
    #pragma unroll
    for (int mi = 0; mi < 8; ++mi)
        #pragma unroll
        for (int ni = 0; ni < 4; ++ni)
            #pragma unroll
            for (int j = 0; j < 4; ++j)
                C[(size_t)(rbase + mi * 16 + rq + j) * NROWS + cbase + ni * 16 + cn] =
                    acc[mi][ni][j] * 20.0f;
}

extern "C" void kernel_launch(void* const* d_in, const int* in_sizes, int n_in,
                              void* d_out, int out_size, void* d_ws, size_t ws_size,
                              hipStream_t stream) {
    (void)in_sizes; (void)n_in; (void)d_ws; (void)ws_size; (void)out_size;
    const float* x1 = (const float*)d_in[0];
    const float* x2 = (const float*)d_in[1];
    float* out = (float*)d_out;

    norm_cast_kernel<<<2 * NROWS, 256, 0, stream>>>(x1, x2);
    gemm8_kernel<<<(NROWS / 256) * (NROWS / 256), 512, 0, stream>>>(out);
}